// Round 6
// baseline (247.510 us; speedup 1.0000x reference)
//
#include <hip/hip_runtime.h>
#include <float.h>
#include <math.h>

#define BATCH 8
#define NPTS 4096
#define KNN 10
#define BN (BATCH * NPTS)          // 32768 points per cloud
#define TPB 256                    // 4 waves
#define WAVES 4                    // scan segments, one per wave (wave-uniform LDS reads)
#define QPB 64                     // queries per block (1 per lane)
#define HALF 2048                  // points staged per pass (32 KiB as float4)
#define SEGC (HALF / WAVES)        // 512 candidates per wave per pass
#define GRIDX (NPTS / QPB)         // 64
#define TOTAL_BLOCKS (GRIDX * BATCH * 2)  // 1024
#define KB_STRIDE 11               // merge keybuf row stride (odd)

__device__ inline float med3f(float x, float a, float b) {
    return __builtin_amdgcn_fmed3f(x, a, b);
}

// branchless sorted insert of key into ascending k[0..9] (drop largest);
// all 9 med3 read pre-insert values -> depth-1 dependency chain
#define INSERT(karr, key)                                              \
    do {                                                               \
        _Pragma("unroll")                                              \
        for (int _j = KNN - 1; _j >= 1; --_j)                          \
            karr[_j] = med3f((key), karr[_j - 1], karr[_j]);           \
        karr[0] = fminf((key), karr[0]);                               \
    } while (0)

// Eigenvector of smallest eigenvalue of symmetric 3x3
__device__ inline void smallest_eigvec(float a00, float a01, float a02,
                                       float a11, float a12, float a22,
                                       float& vx, float& vy, float& vz) {
    float p1 = a01 * a01 + a02 * a02 + a12 * a12;
    float q = (a00 + a11 + a22) * (1.0f / 3.0f);
    float b00 = a00 - q, b11 = a11 - q, b22 = a22 - q;
    float p2 = b00 * b00 + b11 * b11 + b22 * b22 + 2.0f * p1;
    float p = sqrtf(p2 * (1.0f / 6.0f));
    if (p < 1e-20f) { vx = 1.0f; vy = 0.0f; vz = 0.0f; return; }
    float ip = 1.0f / p;
    float c00 = b00 * ip, c01 = a01 * ip, c02 = a02 * ip;
    float c11 = b11 * ip, c12 = a12 * ip, c22 = b22 * ip;
    float detB = c00 * (c11 * c22 - c12 * c12)
               - c01 * (c01 * c22 - c12 * c02)
               + c02 * (c01 * c12 - c11 * c02);
    float r = 0.5f * detB;
    r = fminf(1.0f, fmaxf(-1.0f, r));
    float phi = acosf(r) * (1.0f / 3.0f);
    float lmin = q + 2.0f * p * cosf(phi + 2.0943951023931953f);

    float m00 = a00 - lmin, m11 = a11 - lmin, m22 = a22 - lmin;
    float r0x = m00, r0y = a01, r0z = a02;
    float r1x = a01, r1y = m11, r1z = a12;
    float r2x = a02, r2y = a12, r2z = m22;
    float c0x = r0y * r1z - r0z * r1y, c0y = r0z * r1x - r0x * r1z, c0z = r0x * r1y - r0y * r1x;
    float c1x = r0y * r2z - r0z * r2y, c1y = r0z * r2x - r0x * r2z, c1z = r0x * r2y - r0y * r2x;
    float c2x = r1y * r2z - r1z * r2y, c2y = r1z * r2x - r1x * r2z, c2z = r1x * r2y - r1y * r2x;
    float n0 = c0x * c0x + c0y * c0y + c0z * c0z;
    float n1 = c1x * c1x + c1y * c1y + c1z * c1z;
    float n2 = c2x * c2x + c2y * c2y + c2z * c2z;
    float bx = c0x, by = c0y, bz = c0z, bnm = n0;
    if (n1 > bnm) { bx = c1x; by = c1y; bz = c1z; bnm = n1; }
    if (n2 > bnm) { bx = c2x; by = c2y; bz = c2z; bnm = n2; }
    if (bnm < 1e-30f) { vx = 1.0f; vy = 0.0f; vz = 0.0f; return; }
    float inv = rsqrtf(bnm);
    vx = bx * inv; vy = by * inv; vz = bz * inv;
}

__global__ void init_counter_kernel(unsigned* __restrict__ counter) {
    if (threadIdx.x == 0) *counter = 0u;
}

// 256 threads = 4 waves; lane l owns query base+l; wave w scans segment w with
// wave-uniform broadcast LDS reads + 1-deep prefetch. Cloud staged in two
// 32 KiB half-passes -> 4 blocks/CU. Last-finishing block reduces the loss.
__global__ __launch_bounds__(TPB, 4) void knn_normals_fused(
    const float* __restrict__ pred, const float* __restrict__ gt,
    float* __restrict__ nbuf /* [BN][6] = pn.xyz, gn.xyz */,
    unsigned* __restrict__ counter, float* __restrict__ out) {
    __shared__ float4 pts[HALF + 1];   // +1: prefetch overrun pad; aliased as keybuf
    __shared__ float red[TPB];
    __shared__ int islast;

    const int b = blockIdx.y;
    const int cloud = blockIdx.z;
    const float* __restrict__ base = (cloud == 0 ? pred : gt) + b * 3 * NPTS;
    const int tid = threadIdx.x;
    const int lane = tid & 63;
    const int w = tid >> 6;            // wave id = segment id

    const int pt = blockIdx.x * QPB + lane;
    const float ax = -2.0f * base[pt];
    const float ay = -2.0f * base[NPTS + pt];
    const float az = -2.0f * base[2 * NPTS + pt];

    float k[KNN];
#pragma unroll
    for (int j = 0; j < KNN; ++j) k[j] = FLT_MAX;

    const int s0 = w * SEGC;           // wave-uniform segment offset
    for (int pass = 0; pass < 2; ++pass) {
        const int pb = pass * HALF;
#pragma unroll
        for (int i = tid; i < HALF; i += TPB) {
            float x = base[pb + i];
            float y = base[NPTS + pb + i];
            float z = base[2 * NPTS + pb + i];
            pts[i] = make_float4(x, y, z, fmaf(x, x, fmaf(y, y, z * z)));
        }
        __syncthreads();

        const unsigned gb = (unsigned)(pb + s0);
        float4 p = pts[s0];            // broadcast read, prefetched
#pragma unroll 4
        for (int c = 0; c < SEGC; ++c) {
            float4 pnext = pts[s0 + c + 1];   // next candidate in flight (pad on last)
            // shifted sq-distance d' = |p|^2 - 2 p.q (per-query const shift,
            // order-preserving); candidate index packed into low 12 bits
            float d = fmaf(p.z, az, fmaf(p.y, ay, fmaf(p.x, ax, p.w)));
            float key = __uint_as_float((__float_as_uint(d) & 0xFFFFF000u) | (gb + c));
            INSERT(k, key);
            p = pnext;
        }
        __syncthreads();               // scan done before restage / keybuf aliasing
    }

    // waves 1..3 dump sorted-10s; wave 0 merges (direct array access only)
    float* keybuf = (float*)pts;
    if (w != 0) {
        float* dst = keybuf + ((w - 1) * 64 + lane) * KB_STRIDE;
#pragma unroll
        for (int j = 0; j < KNN; ++j) dst[j] = k[j];
    }
    __syncthreads();

    if (w == 0) {
        for (int s = 0; s < WAVES - 1; ++s) {
            const float* src = keybuf + (s * 64 + lane) * KB_STRIDE;
#pragma unroll
            for (int j = 0; j < KNN; ++j) {
                float sk = src[j];
                INSERT(k, sk);
            }
        }

        // raw-moment covariance of the 10 neighbors
        float sx = 0.f, sy = 0.f, sz = 0.f;
        float sxx = 0.f, sxy = 0.f, sxz = 0.f, syy = 0.f, syz = 0.f, szz = 0.f;
#pragma unroll
        for (int j = 0; j < KNN; ++j) {
            int idx = (int)(__float_as_uint(k[j]) & 0xFFFu);
            float x = base[idx], y = base[NPTS + idx], z = base[2 * NPTS + idx];
            sx += x; sy += y; sz += z;
            sxx = fmaf(x, x, sxx); sxy = fmaf(x, y, sxy); sxz = fmaf(x, z, sxz);
            syy = fmaf(y, y, syy); syz = fmaf(y, z, syz); szz = fmaf(z, z, szz);
        }
        const float iK = 1.0f / KNN;
        float mx = sx * iK, my = sy * iK, mz = sz * iK;
        float cxx = sxx * iK - mx * mx, cxy = sxy * iK - mx * my, cxz = sxz * iK - mx * mz;
        float cyy = syy * iK - my * my, cyz = syz * iK - my * mz, czz = szz * iK - mz * mz;

        float vx, vy, vz;
        smallest_eigvec(cxx, cxy, cxz, cyy, cyz, czz, vx, vy, vz);

        float* dst = nbuf + (size_t)(b * NPTS + pt) * 6 + 3 * cloud;
        dst[0] = vx; dst[1] = vy; dst[2] = vz;
    }

    // completion protocol: publish nbuf, last block computes the loss
    __threadfence();
    __syncthreads();
    if (tid == 0) {
        unsigned old = atomicAdd(counter, 1u);
        islast = (old == TOTAL_BLOCKS - 1) ? 1 : 0;
    }
    __syncthreads();

    if (islast) {
        __threadfence();   // acquire
        float acc = 0.f;
        for (int i = tid; i < BN; i += TPB) {
            const float* v = nbuf + (size_t)i * 6;
            float px = v[0], py = v[1], pz = v[2];
            float gx = v[3], gy = v[4], gz = v[5];
            float dot = px * gx + py * gy + pz * gz;
            float npn = sqrtf(px * px + py * py + pz * pz);
            float ngn = sqrtf(gx * gx + gy * gy + gz * gz);
            float denom = fmaxf(npn * ngn, 1e-8f);
            acc += 1.0f - fabsf(dot / denom);
        }
        red[tid] = acc;
        __syncthreads();
        for (int s = TPB / 2; s > 0; s >>= 1) {
            if (tid < s) red[tid] += red[tid + s];
            __syncthreads();
        }
        if (tid == 0) out[0] = red[0] * (1.0f / BN);
    }
}

extern "C" void kernel_launch(void* const* d_in, const int* in_sizes, int n_in,
                              void* d_out, int out_size, void* d_ws, size_t ws_size,
                              hipStream_t stream) {
    const float* pred = (const float*)d_in[0];
    const float* gt = (const float*)d_in[1];
    float* out = (float*)d_out;
    unsigned* counter = (unsigned*)d_ws;        // first 64 B slot
    float* nbuf = (float*)d_ws + 16;            // BN*6 floats = 768 KiB

    init_counter_kernel<<<1, 64, 0, stream>>>(counter);
    dim3 grid(GRIDX, BATCH, 2);                 // 64 x 8 x 2 = 1024 blocks
    knn_normals_fused<<<grid, TPB, 0, stream>>>(pred, gt, nbuf, counter, out);
}

// Round 7
// 182.644 us; speedup vs baseline: 1.3552x; 1.3552x over previous
//
#include <hip/hip_runtime.h>
#include <float.h>
#include <math.h>

#define BATCH 8
#define NPTS 4096
#define KNN 10
#define BN (BATCH * NPTS)          // 32768 points per cloud
#define TPB 512                    // 8 waves
#define WAVES 8                    // scan segments, one per wave (wave-uniform LDS reads)
#define QPB 128                    // queries per block = 64 lanes x Q=2
#define HALFPTS 2048               // points staged per pass (32 KiB as float4)
#define SEGC (HALFPTS / WAVES)     // 256 candidates per wave per pass
#define GRIDX (NPTS / QPB)         // 32  -> grid 32x8 = 256 blocks = 1/CU
#define KB_STRIDE (2 * KNN + 1)    // 21: merge keybuf row stride (21 coprime 32 -> 2-way max)

__device__ inline float med3f(float x, float a, float b) {
    return __builtin_amdgcn_fmed3f(x, a, b);
}

// branchless sorted insert of key into ascending k[0..9] (drop largest)
#define INSERT(karr, key)                                              \
    do {                                                               \
        _Pragma("unroll")                                              \
        for (int _j = KNN - 1; _j >= 1; --_j)                          \
            karr[_j] = med3f((key), karr[_j - 1], karr[_j]);           \
        karr[0] = fminf((key), karr[0]);                               \
    } while (0)

// Eigenvector of smallest eigenvalue of symmetric 3x3
__device__ inline void smallest_eigvec(float a00, float a01, float a02,
                                       float a11, float a12, float a22,
                                       float& vx, float& vy, float& vz) {
    float p1 = a01 * a01 + a02 * a02 + a12 * a12;
    float q = (a00 + a11 + a22) * (1.0f / 3.0f);
    float b00 = a00 - q, b11 = a11 - q, b22 = a22 - q;
    float p2 = b00 * b00 + b11 * b11 + b22 * b22 + 2.0f * p1;
    float p = sqrtf(p2 * (1.0f / 6.0f));
    if (p < 1e-20f) { vx = 1.0f; vy = 0.0f; vz = 0.0f; return; }
    float ip = 1.0f / p;
    float c00 = b00 * ip, c01 = a01 * ip, c02 = a02 * ip;
    float c11 = b11 * ip, c12 = a12 * ip, c22 = b22 * ip;
    float detB = c00 * (c11 * c22 - c12 * c12)
               - c01 * (c01 * c22 - c12 * c02)
               + c02 * (c01 * c12 - c11 * c02);
    float r = 0.5f * detB;
    r = fminf(1.0f, fmaxf(-1.0f, r));
    float phi = acosf(r) * (1.0f / 3.0f);
    float lmin = q + 2.0f * p * cosf(phi + 2.0943951023931953f);

    float m00 = a00 - lmin, m11 = a11 - lmin, m22 = a22 - lmin;
    float r0x = m00, r0y = a01, r0z = a02;
    float r1x = a01, r1y = m11, r1z = a12;
    float r2x = a02, r2y = a12, r2z = m22;
    float c0x = r0y * r1z - r0z * r1y, c0y = r0z * r1x - r0x * r1z, c0z = r0x * r1y - r0y * r1x;
    float c1x = r0y * r2z - r0z * r2y, c1y = r0z * r2x - r0x * r2z, c1z = r0x * r2y - r0y * r2x;
    float c2x = r1y * r2z - r1z * r2y, c2y = r1z * r2x - r1x * r2z, c2z = r1x * r2y - r1y * r2x;
    float n0 = c0x * c0x + c0y * c0y + c0z * c0z;
    float n1 = c1x * c1x + c1y * c1y + c1z * c1z;
    float n2 = c2x * c2x + c2y * c2y + c2z * c2z;
    float bx = c0x, by = c0y, bz = c0z, bnm = n0;
    if (n1 > bnm) { bx = c1x; by = c1y; bz = c1z; bnm = n1; }
    if (n2 > bnm) { bx = c2x; by = c2y; bz = c2z; bnm = n2; }
    if (bnm < 1e-30f) { vx = 1.0f; vy = 0.0f; vz = 0.0f; return; }
    float inv = rsqrtf(bnm);
    vx = bx * inv; vy = by * inv; vz = bz * inv;
}

// stage HALFPTS points (SoA planes -> float4 x,y,z,|p|^2) into LDS
#define STAGE(basep, pb)                                               \
    do {                                                               \
        for (int _i = tid; _i < HALFPTS; _i += TPB) {                  \
            float _x = (basep)[(pb) + _i];                             \
            float _y = (basep)[NPTS + (pb) + _i];                      \
            float _z = (basep)[2 * NPTS + (pb) + _i];                  \
            pts[_i] = make_float4(_x, _y, _z, fmaf(_x, _x, fmaf(_y, _y, _z * _z))); \
        }                                                              \
    } while (0)

// full kNN of queries (pt0, pt1) over cloud `basep`; result (wave 0 only)
// in ka/kb. Direct pts[] reads + unroll 8: compiler batches 8 ds_read_b128.
#define SCAN_CLOUD(basep, ka, kb)                                      \
    do {                                                               \
        _Pragma("unroll")                                              \
        for (int _j = 0; _j < KNN; ++_j) { ka[_j] = FLT_MAX; kb[_j] = FLT_MAX; } \
        const float _a0x = -2.0f * (basep)[pt0];                       \
        const float _a0y = -2.0f * (basep)[NPTS + pt0];                \
        const float _a0z = -2.0f * (basep)[2 * NPTS + pt0];            \
        const float _a1x = -2.0f * (basep)[pt1];                       \
        const float _a1y = -2.0f * (basep)[NPTS + pt1];                \
        const float _a1z = -2.0f * (basep)[2 * NPTS + pt1];            \
        for (int _pass = 0; _pass < 2; ++_pass) {                      \
            const int _pb = _pass * HALFPTS;                           \
            STAGE(basep, _pb);                                         \
            __syncthreads();                                           \
            const unsigned _gb = (unsigned)(_pb + s0);                 \
            _Pragma("unroll 8")                                        \
            for (int _c = 0; _c < SEGC; ++_c) {                        \
                float4 _p = pts[s0 + _c];                              \
                float _d0 = fmaf(_p.z, _a0z, fmaf(_p.y, _a0y, fmaf(_p.x, _a0x, _p.w))); \
                float _d1 = fmaf(_p.z, _a1z, fmaf(_p.y, _a1y, fmaf(_p.x, _a1x, _p.w))); \
                unsigned _gi = _gb + (unsigned)_c;                     \
                float _k0 = __uint_as_float((__float_as_uint(_d0) & 0xFFFFF000u) | _gi); \
                float _k1 = __uint_as_float((__float_as_uint(_d1) & 0xFFFFF000u) | _gi); \
                INSERT(ka, _k0);                                       \
                INSERT(kb, _k1);                                       \
            }                                                          \
            __syncthreads();                                           \
        }                                                              \
        /* tree merge 8->4->2->1; keybuf aliases dead stage buffer */  \
        for (int _half = WAVES / 2; _half >= 1; _half >>= 1) {         \
            if (w >= _half && w < 2 * _half) {                         \
                float* _dst = keybuf + ((w - _half) * 64 + lane) * KB_STRIDE; \
                _Pragma("unroll")                                      \
                for (int _j = 0; _j < KNN; ++_j) { _dst[_j] = ka[_j]; _dst[KNN + _j] = kb[_j]; } \
            }                                                          \
            __syncthreads();                                           \
            if (w < _half) {                                           \
                const float* _src = keybuf + (w * 64 + lane) * KB_STRIDE; \
                _Pragma("unroll")                                      \
                for (int _j = 0; _j < KNN; ++_j) {                     \
                    float _sa = _src[_j], _sb = _src[KNN + _j];        \
                    INSERT(ka, _sa);                                   \
                    INSERT(kb, _sb);                                   \
                }                                                      \
            }                                                          \
            __syncthreads();                                           \
        }                                                              \
    } while (0)

// covariance of the 10 neighbors (indices in karr low 12 bits) + eigenvector
#define COMPUTE_NORMAL(karr, basep, vx, vy, vz)                        \
    do {                                                               \
        float _sx = 0.f, _sy = 0.f, _sz = 0.f;                         \
        float _sxx = 0.f, _sxy = 0.f, _sxz = 0.f;                      \
        float _syy = 0.f, _syz = 0.f, _szz = 0.f;                      \
        _Pragma("unroll")                                              \
        for (int _j = 0; _j < KNN; ++_j) {                             \
            int _idx = (int)(__float_as_uint(karr[_j]) & 0xFFFu);      \
            float _x = (basep)[_idx];                                  \
            float _y = (basep)[NPTS + _idx];                           \
            float _z = (basep)[2 * NPTS + _idx];                       \
            _sx += _x; _sy += _y; _sz += _z;                           \
            _sxx = fmaf(_x, _x, _sxx); _sxy = fmaf(_x, _y, _sxy); _sxz = fmaf(_x, _z, _sxz); \
            _syy = fmaf(_y, _y, _syy); _syz = fmaf(_y, _z, _syz); _szz = fmaf(_z, _z, _szz); \
        }                                                              \
        const float _iK = 1.0f / KNN;                                  \
        float _mx = _sx * _iK, _my = _sy * _iK, _mz = _sz * _iK;       \
        smallest_eigvec(_sxx * _iK - _mx * _mx, _sxy * _iK - _mx * _my, \
                        _sxz * _iK - _mx * _mz, _syy * _iK - _my * _my, \
                        _syz * _iK - _my * _mz, _szz * _iK - _mz * _mz, \
                        vx, vy, vz);                                   \
    } while (0)

__global__ void zero_out_kernel(float* __restrict__ out) {
    if (threadIdx.x == 0) out[0] = 0.0f;
}

// One block = 128 points of one batch, BOTH clouds. 8 waves; lane l owns
// points (base+l, base+l+64); wave w scans segment w (wave-uniform broadcast
// LDS reads, Q=2 amortization). Loss computed in-block, one atomicAdd.
__global__ __launch_bounds__(TPB, 2) void knn_normal_loss(
    const float* __restrict__ pred, const float* __restrict__ gt,
    float* __restrict__ out) {
    __shared__ float4 pts[HALFPTS];   // 32 KiB; aliased as merge keybuf

    const int b = blockIdx.y;
    const float* __restrict__ baseP = pred + b * 3 * NPTS;
    const float* __restrict__ baseG = gt + b * 3 * NPTS;
    const int tid = threadIdx.x;
    const int lane = tid & 63;
    const int w = tid >> 6;           // wave id = segment id
    const int s0 = w * SEGC;          // wave-uniform segment offset
    float* keybuf = (float*)pts;

    const int pt0 = blockIdx.x * QPB + lane;
    const int pt1 = pt0 + 64;

    float kP0[KNN], kP1[KNN];         // pred top-10 (final in wave 0)
    float kG0[KNN], kG1[KNN];         // gt   top-10 (final in wave 0)

    SCAN_CLOUD(baseP, kP0, kP1);
    SCAN_CLOUD(baseG, kG0, kG1);

    if (w == 0) {
        float acc;
        {
            float pvx, pvy, pvz, gvx, gvy, gvz;
            COMPUTE_NORMAL(kP0, baseP, pvx, pvy, pvz);
            COMPUTE_NORMAL(kG0, baseG, gvx, gvy, gvz);
            float dot = pvx * gvx + pvy * gvy + pvz * gvz;
            float npn = sqrtf(pvx * pvx + pvy * pvy + pvz * pvz);
            float ngn = sqrtf(gvx * gvx + gvy * gvy + gvz * gvz);
            acc = 1.0f - fabsf(dot / fmaxf(npn * ngn, 1e-8f));
        }
        {
            float pvx, pvy, pvz, gvx, gvy, gvz;
            COMPUTE_NORMAL(kP1, baseP, pvx, pvy, pvz);
            COMPUTE_NORMAL(kG1, baseG, gvx, gvy, gvz);
            float dot = pvx * gvx + pvy * gvy + pvz * gvz;
            float npn = sqrtf(pvx * pvx + pvy * pvy + pvz * pvz);
            float ngn = sqrtf(gvx * gvx + gvy * gvy + gvz * gvz);
            acc += 1.0f - fabsf(dot / fmaxf(npn * ngn, 1e-8f));
        }
        // wave reduction, then one atomic per block
        for (int off = 32; off > 0; off >>= 1) acc += __shfl_down(acc, off);
        if (lane == 0) atomicAdd(out, acc * (1.0f / (float)BN));
    }
}

extern "C" void kernel_launch(void* const* d_in, const int* in_sizes, int n_in,
                              void* d_out, int out_size, void* d_ws, size_t ws_size,
                              hipStream_t stream) {
    const float* pred = (const float*)d_in[0];
    const float* gt = (const float*)d_in[1];
    float* out = (float*)d_out;

    zero_out_kernel<<<1, 64, 0, stream>>>(out);
    dim3 grid(GRIDX, BATCH);          // 32 x 8 = 256 blocks (1 per CU)
    knn_normal_loss<<<grid, TPB, 0, stream>>>(pred, gt, out);
}

// Round 8
// 179.181 us; speedup vs baseline: 1.3813x; 1.0193x over previous
//
#include <hip/hip_runtime.h>
#include <float.h>
#include <math.h>

#define BATCH 8
#define NPTS 4096
#define KNN 10
#define BN (BATCH * NPTS)          // 32768 points per cloud
#define TPB 512                    // 8 waves
#define WAVES 8                    // scan segments, one per wave (wave-uniform LDS reads)
#define QPB 128                    // queries per block = 64 lanes x Q=2
#define HALFPTS 2048               // points staged per pass (32 KiB as float4)
#define SEGC (HALFPTS / WAVES)     // 256 candidates per wave per pass
#define GRIDX (NPTS / QPB)         // 32  -> grid 32x8 = 256 blocks = 1/CU
#define KB_STRIDE (2 * KNN + 1)    // 21: merge keybuf row stride

__device__ inline float med3f(float x, float a, float b) {
    return __builtin_amdgcn_fmed3f(x, a, b);
}

// branchless sorted insert of key into ascending k[0..9] (drop largest);
// all 9 med3 read pre-insert values -> the 10 ops are mutually independent
#define INSERT(karr, key)                                              \
    do {                                                               \
        _Pragma("unroll")                                              \
        for (int _j = KNN - 1; _j >= 1; --_j)                          \
            karr[_j] = med3f((key), karr[_j - 1], karr[_j]);           \
        karr[0] = fminf((key), karr[0]);                               \
    } while (0)

// distance + pack + two inserts for one candidate float4 _p at index _gi
#define PROC(_p, _gi, ka, kb)                                          \
    do {                                                               \
        float _d0 = fmaf((_p).z, a0z, fmaf((_p).y, a0y, fmaf((_p).x, a0x, (_p).w))); \
        float _d1 = fmaf((_p).z, a1z, fmaf((_p).y, a1y, fmaf((_p).x, a1x, (_p).w))); \
        float _k0 = __uint_as_float((__float_as_uint(_d0) & 0xFFFFF000u) | (_gi)); \
        float _k1 = __uint_as_float((__float_as_uint(_d1) & 0xFFFFF000u) | (_gi)); \
        INSERT(ka, _k0);                                               \
        INSERT(kb, _k1);                                               \
    } while (0)

// Eigenvector of smallest eigenvalue of symmetric 3x3
__device__ inline void smallest_eigvec(float a00, float a01, float a02,
                                       float a11, float a12, float a22,
                                       float& vx, float& vy, float& vz) {
    float p1 = a01 * a01 + a02 * a02 + a12 * a12;
    float q = (a00 + a11 + a22) * (1.0f / 3.0f);
    float b00 = a00 - q, b11 = a11 - q, b22 = a22 - q;
    float p2 = b00 * b00 + b11 * b11 + b22 * b22 + 2.0f * p1;
    float p = sqrtf(p2 * (1.0f / 6.0f));
    if (p < 1e-20f) { vx = 1.0f; vy = 0.0f; vz = 0.0f; return; }
    float ip = 1.0f / p;
    float c00 = b00 * ip, c01 = a01 * ip, c02 = a02 * ip;
    float c11 = b11 * ip, c12 = a12 * ip, c22 = b22 * ip;
    float detB = c00 * (c11 * c22 - c12 * c12)
               - c01 * (c01 * c22 - c12 * c02)
               + c02 * (c01 * c12 - c11 * c02);
    float r = 0.5f * detB;
    r = fminf(1.0f, fmaxf(-1.0f, r));
    float phi = acosf(r) * (1.0f / 3.0f);
    float lmin = q + 2.0f * p * cosf(phi + 2.0943951023931953f);

    float m00 = a00 - lmin, m11 = a11 - lmin, m22 = a22 - lmin;
    float r0x = m00, r0y = a01, r0z = a02;
    float r1x = a01, r1y = m11, r1z = a12;
    float r2x = a02, r2y = a12, r2z = m22;
    float c0x = r0y * r1z - r0z * r1y, c0y = r0z * r1x - r0x * r1z, c0z = r0x * r1y - r0y * r1x;
    float c1x = r0y * r2z - r0z * r2y, c1y = r0z * r2x - r0x * r2z, c1z = r0x * r2y - r0y * r2x;
    float c2x = r1y * r2z - r1z * r2y, c2y = r1z * r2x - r1x * r2z, c2z = r1x * r2y - r1y * r2x;
    float n0 = c0x * c0x + c0y * c0y + c0z * c0z;
    float n1 = c1x * c1x + c1y * c1y + c1z * c1z;
    float n2 = c2x * c2x + c2y * c2y + c2z * c2z;
    float bx = c0x, by = c0y, bz = c0z, bnm = n0;
    if (n1 > bnm) { bx = c1x; by = c1y; bz = c1z; bnm = n1; }
    if (n2 > bnm) { bx = c2x; by = c2y; bz = c2z; bnm = n2; }
    if (bnm < 1e-30f) { vx = 1.0f; vy = 0.0f; vz = 0.0f; return; }
    float inv = rsqrtf(bnm);
    vx = bx * inv; vy = by * inv; vz = bz * inv;
}

// stage HALFPTS points (SoA planes -> float4 x,y,z,|p|^2) into LDS
#define STAGE(basep, pb)                                               \
    do {                                                               \
        for (int _i = tid; _i < HALFPTS; _i += TPB) {                  \
            float _x = (basep)[(pb) + _i];                             \
            float _y = (basep)[NPTS + (pb) + _i];                      \
            float _z = (basep)[2 * NPTS + (pb) + _i];                  \
            pts[_i] = make_float4(_x, _y, _z, fmaf(_x, _x, fmaf(_y, _y, _z * _z))); \
        }                                                              \
    } while (0)

// full kNN of queries (pt0, pt1) over cloud `basep`; result (wave 0 only)
// lands in ka/kb. Manual 8-deep load batch (named float4s p0..p7) keeps >=8
// ds_read_b128 in flight regardless of the backend's VGPR heuristic.
#define SCAN_CLOUD(basep, ka, kb)                                      \
    do {                                                               \
        _Pragma("unroll")                                              \
        for (int _j = 0; _j < KNN; ++_j) { ka[_j] = FLT_MAX; kb[_j] = FLT_MAX; } \
        const float a0x = -2.0f * (basep)[pt0];                        \
        const float a0y = -2.0f * (basep)[NPTS + pt0];                 \
        const float a0z = -2.0f * (basep)[2 * NPTS + pt0];             \
        const float a1x = -2.0f * (basep)[pt1];                        \
        const float a1y = -2.0f * (basep)[NPTS + pt1];                 \
        const float a1z = -2.0f * (basep)[2 * NPTS + pt1];             \
        for (int _pass = 0; _pass < 2; ++_pass) {                      \
            const int _pb = _pass * HALFPTS;                           \
            STAGE(basep, _pb);                                         \
            __syncthreads();                                           \
            const unsigned _gb = (unsigned)(_pb + s0);                 \
            for (int _c = 0; _c < SEGC; _c += 8) {                     \
                float4 p0 = pts[s0 + _c + 0];                          \
                float4 p1 = pts[s0 + _c + 1];                          \
                float4 p2 = pts[s0 + _c + 2];                          \
                float4 p3 = pts[s0 + _c + 3];                          \
                float4 p4 = pts[s0 + _c + 4];                          \
                float4 p5 = pts[s0 + _c + 5];                          \
                float4 p6 = pts[s0 + _c + 6];                          \
                float4 p7 = pts[s0 + _c + 7];                          \
                unsigned _gi = _gb + (unsigned)_c;                     \
                PROC(p0, _gi + 0, ka, kb);                             \
                PROC(p1, _gi + 1, ka, kb);                             \
                PROC(p2, _gi + 2, ka, kb);                             \
                PROC(p3, _gi + 3, ka, kb);                             \
                PROC(p4, _gi + 4, ka, kb);                             \
                PROC(p5, _gi + 5, ka, kb);                             \
                PROC(p6, _gi + 6, ka, kb);                             \
                PROC(p7, _gi + 7, ka, kb);                             \
            }                                                          \
            __syncthreads();                                           \
        }                                                              \
        /* tree merge 8->4->2->1; keybuf aliases dead stage buffer */  \
        for (int _half = WAVES / 2; _half >= 1; _half >>= 1) {         \
            if (w >= _half && w < 2 * _half) {                         \
                float* _dst = keybuf + ((w - _half) * 64 + lane) * KB_STRIDE; \
                _Pragma("unroll")                                      \
                for (int _j = 0; _j < KNN; ++_j) { _dst[_j] = ka[_j]; _dst[KNN + _j] = kb[_j]; } \
            }                                                          \
            __syncthreads();                                           \
            if (w < _half) {                                           \
                const float* _src = keybuf + (w * 64 + lane) * KB_STRIDE; \
                _Pragma("unroll")                                      \
                for (int _j = 0; _j < KNN; ++_j) {                     \
                    float _sa = _src[_j], _sb = _src[KNN + _j];        \
                    INSERT(ka, _sa);                                   \
                    INSERT(kb, _sb);                                   \
                }                                                      \
            }                                                          \
            __syncthreads();                                           \
        }                                                              \
    } while (0)

// covariance of the 10 neighbors (indices in karr low 12 bits) + eigenvector
#define COMPUTE_NORMAL(karr, basep, vx, vy, vz)                        \
    do {                                                               \
        float _sx = 0.f, _sy = 0.f, _sz = 0.f;                         \
        float _sxx = 0.f, _sxy = 0.f, _sxz = 0.f;                      \
        float _syy = 0.f, _syz = 0.f, _szz = 0.f;                      \
        _Pragma("unroll")                                              \
        for (int _j = 0; _j < KNN; ++_j) {                             \
            int _idx = (int)(__float_as_uint(karr[_j]) & 0xFFFu);      \
            float _x = (basep)[_idx];                                  \
            float _y = (basep)[NPTS + _idx];                           \
            float _z = (basep)[2 * NPTS + _idx];                       \
            _sx += _x; _sy += _y; _sz += _z;                           \
            _sxx = fmaf(_x, _x, _sxx); _sxy = fmaf(_x, _y, _sxy); _sxz = fmaf(_x, _z, _sxz); \
            _syy = fmaf(_y, _y, _syy); _syz = fmaf(_y, _z, _syz); _szz = fmaf(_z, _z, _szz); \
        }                                                              \
        const float _iK = 1.0f / KNN;                                  \
        float _mx = _sx * _iK, _my = _sy * _iK, _mz = _sz * _iK;       \
        smallest_eigvec(_sxx * _iK - _mx * _mx, _sxy * _iK - _mx * _my, \
                        _sxz * _iK - _mx * _mz, _syy * _iK - _my * _my, \
                        _syz * _iK - _my * _mz, _szz * _iK - _mz * _mz, \
                        vx, vy, vz);                                   \
    } while (0)

__global__ void zero_out_kernel(float* __restrict__ out) {
    if (threadIdx.x == 0) out[0] = 0.0f;
}

// One block = 128 points of one batch, BOTH clouds. 8 waves; lane l owns
// points (base+l, base+l+64); wave w scans segment w (wave-uniform broadcast
// LDS reads, Q=2 amortization). Loss computed in-block, one atomicAdd.
__global__ __launch_bounds__(TPB, 2) void knn_normal_loss(
    const float* __restrict__ pred, const float* __restrict__ gt,
    float* __restrict__ out) {
    __shared__ float4 pts[HALFPTS];   // 32 KiB; aliased as merge keybuf

    const int b = blockIdx.y;
    const float* __restrict__ baseP = pred + b * 3 * NPTS;
    const float* __restrict__ baseG = gt + b * 3 * NPTS;
    const int tid = threadIdx.x;
    const int lane = tid & 63;
    const int w = tid >> 6;           // wave id = segment id
    const int s0 = w * SEGC;          // wave-uniform segment offset
    float* keybuf = (float*)pts;

    const int pt0 = blockIdx.x * QPB + lane;
    const int pt1 = pt0 + 64;

    float kP0[KNN], kP1[KNN];         // pred top-10 (final in wave 0)
    float kG0[KNN], kG1[KNN];         // gt   top-10 (final in wave 0)

    SCAN_CLOUD(baseP, kP0, kP1);
    SCAN_CLOUD(baseG, kG0, kG1);

    if (w == 0) {
        float acc;
        {
            float pvx, pvy, pvz, gvx, gvy, gvz;
            COMPUTE_NORMAL(kP0, baseP, pvx, pvy, pvz);
            COMPUTE_NORMAL(kG0, baseG, gvx, gvy, gvz);
            float dot = pvx * gvx + pvy * gvy + pvz * gvz;
            float npn = sqrtf(pvx * pvx + pvy * pvy + pvz * pvz);
            float ngn = sqrtf(gvx * gvx + gvy * gvy + gvz * gvz);
            acc = 1.0f - fabsf(dot / fmaxf(npn * ngn, 1e-8f));
        }
        {
            float pvx, pvy, pvz, gvx, gvy, gvz;
            COMPUTE_NORMAL(kP1, baseP, pvx, pvy, pvz);
            COMPUTE_NORMAL(kG1, baseG, gvx, gvy, gvz);
            float dot = pvx * gvx + pvy * gvy + pvz * gvz;
            float npn = sqrtf(pvx * pvx + pvy * pvy + pvz * pvz);
            float ngn = sqrtf(gvx * gvx + gvy * gvy + gvz * gvz);
            acc += 1.0f - fabsf(dot / fmaxf(npn * ngn, 1e-8f));
        }
        // wave reduction, then one atomic per block
        for (int off = 32; off > 0; off >>= 1) acc += __shfl_down(acc, off);
        if (lane == 0) atomicAdd(out, acc * (1.0f / (float)BN));
    }
}

extern "C" void kernel_launch(void* const* d_in, const int* in_sizes, int n_in,
                              void* d_out, int out_size, void* d_ws, size_t ws_size,
                              hipStream_t stream) {
    const float* pred = (const float*)d_in[0];
    const float* gt = (const float*)d_in[1];
    float* out = (float*)d_out;

    zero_out_kernel<<<1, 64, 0, stream>>>(out);
    dim3 grid(GRIDX, BATCH);          // 32 x 8 = 256 blocks (1 per CU)
    knn_normal_loss<<<grid, TPB, 0, stream>>>(pred, gt, out);
}

// Round 9
// 175.311 us; speedup vs baseline: 1.4118x; 1.0221x over previous
//
#include <hip/hip_runtime.h>
#include <float.h>
#include <math.h>

#define BATCH 8
#define NPTS 4096
#define KNN 10
#define BN (BATCH * NPTS)          // 32768 points per cloud
#define TPB 512                    // 8 waves
#define WAVES 8                    // scan segments, one per wave (wave-uniform LDS reads)
#define QPB 128                    // queries per block = 64 lanes x Q=2
#define HALFPTS 2048               // points staged per pass (32 KiB as float4)
#define SEGC (HALFPTS / WAVES)     // 256 candidates per wave per pass
#define GRIDX (NPTS / QPB)         // 32  -> grid 32x8 = 256 blocks = 1/CU
#define KB_STRIDE (2 * KNN + 1)    // 21: merge keybuf row stride

__device__ inline float med3f(float x, float a, float b) {
    return __builtin_amdgcn_fmed3f(x, a, b);
}

// branchless sorted insert of key into ascending k[0..9] (drop largest);
// the 9 med3 all read pre-insert values -> mutually independent
#define INSERT(karr, key)                                              \
    do {                                                               \
        _Pragma("unroll")                                              \
        for (int _j = KNN - 1; _j >= 1; --_j)                          \
            karr[_j] = med3f((key), karr[_j - 1], karr[_j]);           \
        karr[0] = fminf((key), karr[0]);                               \
    } while (0)

// distance + pack + two inserts for one candidate float4 _p at index _gi
#define PROC(_p, _gi, ka, kb)                                          \
    do {                                                               \
        float _d0 = fmaf((_p).z, a0z, fmaf((_p).y, a0y, fmaf((_p).x, a0x, (_p).w))); \
        float _d1 = fmaf((_p).z, a1z, fmaf((_p).y, a1y, fmaf((_p).x, a1x, (_p).w))); \
        float _k0 = __uint_as_float((__float_as_uint(_d0) & 0xFFFFF000u) | (_gi)); \
        float _k1 = __uint_as_float((__float_as_uint(_d1) & 0xFFFFF000u) | (_gi)); \
        INSERT(ka, _k0);                                               \
        INSERT(kb, _k1);                                               \
    } while (0)

#define PROC8(P, _gi, ka, kb)                                          \
    do {                                                               \
        PROC(P##0, (_gi) + 0, ka, kb);                                 \
        PROC(P##1, (_gi) + 1, ka, kb);                                 \
        PROC(P##2, (_gi) + 2, ka, kb);                                 \
        PROC(P##3, (_gi) + 3, ka, kb);                                 \
        PROC(P##4, (_gi) + 4, ka, kb);                                 \
        PROC(P##5, (_gi) + 5, ka, kb);                                 \
        PROC(P##6, (_gi) + 6, ka, kb);                                 \
        PROC(P##7, (_gi) + 7, ka, kb);                                 \
    } while (0)

#define LOAD8(P, _off)                                                 \
    do {                                                               \
        P##0 = pts[(_off) + 0]; P##1 = pts[(_off) + 1];                \
        P##2 = pts[(_off) + 2]; P##3 = pts[(_off) + 3];                \
        P##4 = pts[(_off) + 4]; P##5 = pts[(_off) + 5];                \
        P##6 = pts[(_off) + 6]; P##7 = pts[(_off) + 7];                \
    } while (0)

// Eigenvector of smallest eigenvalue of symmetric 3x3
__device__ inline void smallest_eigvec(float a00, float a01, float a02,
                                       float a11, float a12, float a22,
                                       float& vx, float& vy, float& vz) {
    float p1 = a01 * a01 + a02 * a02 + a12 * a12;
    float q = (a00 + a11 + a22) * (1.0f / 3.0f);
    float b00 = a00 - q, b11 = a11 - q, b22 = a22 - q;
    float p2 = b00 * b00 + b11 * b11 + b22 * b22 + 2.0f * p1;
    float p = sqrtf(p2 * (1.0f / 6.0f));
    if (p < 1e-20f) { vx = 1.0f; vy = 0.0f; vz = 0.0f; return; }
    float ip = 1.0f / p;
    float c00 = b00 * ip, c01 = a01 * ip, c02 = a02 * ip;
    float c11 = b11 * ip, c12 = a12 * ip, c22 = b22 * ip;
    float detB = c00 * (c11 * c22 - c12 * c12)
               - c01 * (c01 * c22 - c12 * c02)
               + c02 * (c01 * c12 - c11 * c02);
    float r = 0.5f * detB;
    r = fminf(1.0f, fmaxf(-1.0f, r));
    float phi = acosf(r) * (1.0f / 3.0f);
    float lmin = q + 2.0f * p * cosf(phi + 2.0943951023931953f);

    float m00 = a00 - lmin, m11 = a11 - lmin, m22 = a22 - lmin;
    float r0x = m00, r0y = a01, r0z = a02;
    float r1x = a01, r1y = m11, r1z = a12;
    float r2x = a02, r2y = a12, r2z = m22;
    float c0x = r0y * r1z - r0z * r1y, c0y = r0z * r1x - r0x * r1z, c0z = r0x * r1y - r0y * r1x;
    float c1x = r0y * r2z - r0z * r2y, c1y = r0z * r2x - r0x * r2z, c1z = r0x * r2y - r0y * r2x;
    float c2x = r1y * r2z - r1z * r2y, c2y = r1z * r2x - r1x * r2z, c2z = r1x * r2y - r1y * r2x;
    float n0 = c0x * c0x + c0y * c0y + c0z * c0z;
    float n1 = c1x * c1x + c1y * c1y + c1z * c1z;
    float n2 = c2x * c2x + c2y * c2y + c2z * c2z;
    float bx = c0x, by = c0y, bz = c0z, bnm = n0;
    if (n1 > bnm) { bx = c1x; by = c1y; bz = c1z; bnm = n1; }
    if (n2 > bnm) { bx = c2x; by = c2y; bz = c2z; bnm = n2; }
    if (bnm < 1e-30f) { vx = 1.0f; vy = 0.0f; vz = 0.0f; return; }
    float inv = rsqrtf(bnm);
    vx = bx * inv; vy = by * inv; vz = bz * inv;
}

// stage HALFPTS points (SoA planes -> float4 x,y,z,|p|^2) into LDS
#define STAGE(basep, pb)                                               \
    do {                                                               \
        for (int _i = tid; _i < HALFPTS; _i += TPB) {                  \
            float _x = (basep)[(pb) + _i];                             \
            float _y = (basep)[NPTS + (pb) + _i];                      \
            float _z = (basep)[2 * NPTS + (pb) + _i];                  \
            pts[_i] = make_float4(_x, _y, _z, fmaf(_x, _x, fmaf(_y, _y, _z * _z))); \
        }                                                              \
    } while (0)

// full kNN of queries (pt0, pt1) over cloud `basep`; result (wave 0 only)
// lands in ka/kb. Register double-buffer (A/B groups of 8 float4) with
// sched_barrier(0) fences: 8 ds_read_b128 stay in flight behind ~480 cyc of
// independent insert VALU -> LDS latency hidden; waits become lgkmcnt(8).
#define SCAN_CLOUD(basep, ka, kb)                                      \
    do {                                                               \
        _Pragma("unroll")                                              \
        for (int _j = 0; _j < KNN; ++_j) { ka[_j] = FLT_MAX; kb[_j] = FLT_MAX; } \
        const float a0x = -2.0f * (basep)[pt0];                        \
        const float a0y = -2.0f * (basep)[NPTS + pt0];                 \
        const float a0z = -2.0f * (basep)[2 * NPTS + pt0];             \
        const float a1x = -2.0f * (basep)[pt1];                        \
        const float a1y = -2.0f * (basep)[NPTS + pt1];                 \
        const float a1z = -2.0f * (basep)[2 * NPTS + pt1];             \
        for (int _pass = 0; _pass < 2; ++_pass) {                      \
            const int _pb = _pass * HALFPTS;                           \
            STAGE(basep, _pb);                                         \
            __syncthreads();                                           \
            const unsigned _gb = (unsigned)(_pb + s0);                 \
            float4 A0, A1, A2, A3, A4, A5, A6, A7;                     \
            float4 B0, B1, B2, B3, B4, B5, B6, B7;                     \
            LOAD8(A, s0);                                              \
            __builtin_amdgcn_sched_barrier(0);                         \
            for (int _c = 0; _c < SEGC; _c += 16) {                    \
                LOAD8(B, s0 + _c + 8);                                 \
                __builtin_amdgcn_sched_barrier(0);                     \
                PROC8(A, _gb + (unsigned)_c, ka, kb);                  \
                __builtin_amdgcn_sched_barrier(0);                     \
                LOAD8(A, s0 + _c + 16);  /* last iter reads pad */     \
                __builtin_amdgcn_sched_barrier(0);                     \
                PROC8(B, _gb + (unsigned)_c + 8u, ka, kb);             \
                __builtin_amdgcn_sched_barrier(0);                     \
            }                                                          \
            __syncthreads();                                           \
        }                                                              \
        /* tree merge 8->4->2->1; keybuf aliases dead stage buffer */  \
        for (int _half = WAVES / 2; _half >= 1; _half >>= 1) {         \
            if (w >= _half && w < 2 * _half) {                         \
                float* _dst = keybuf + ((w - _half) * 64 + lane) * KB_STRIDE; \
                _Pragma("unroll")                                      \
                for (int _j = 0; _j < KNN; ++_j) { _dst[_j] = ka[_j]; _dst[KNN + _j] = kb[_j]; } \
            }                                                          \
            __syncthreads();                                           \
            if (w < _half) {                                           \
                const float* _src = keybuf + (w * 64 + lane) * KB_STRIDE; \
                _Pragma("unroll")                                      \
                for (int _j = 0; _j < KNN; ++_j) {                     \
                    float _sa = _src[_j], _sb = _src[KNN + _j];        \
                    INSERT(ka, _sa);                                   \
                    INSERT(kb, _sb);                                   \
                }                                                      \
            }                                                          \
            __syncthreads();                                           \
        }                                                              \
    } while (0)

// covariance of the 10 neighbors (indices in karr low 12 bits) + eigenvector
#define COMPUTE_NORMAL(karr, basep, vx, vy, vz)                        \
    do {                                                               \
        float _sx = 0.f, _sy = 0.f, _sz = 0.f;                         \
        float _sxx = 0.f, _sxy = 0.f, _sxz = 0.f;                      \
        float _syy = 0.f, _syz = 0.f, _szz = 0.f;                      \
        _Pragma("unroll")                                              \
        for (int _j = 0; _j < KNN; ++_j) {                             \
            int _idx = (int)(__float_as_uint(karr[_j]) & 0xFFFu);      \
            float _x = (basep)[_idx];                                  \
            float _y = (basep)[NPTS + _idx];                           \
            float _z = (basep)[2 * NPTS + _idx];                       \
            _sx += _x; _sy += _y; _sz += _z;                           \
            _sxx = fmaf(_x, _x, _sxx); _sxy = fmaf(_x, _y, _sxy); _sxz = fmaf(_x, _z, _sxz); \
            _syy = fmaf(_y, _y, _syy); _syz = fmaf(_y, _z, _syz); _szz = fmaf(_z, _z, _szz); \
        }                                                              \
        const float _iK = 1.0f / KNN;                                  \
        float _mx = _sx * _iK, _my = _sy * _iK, _mz = _sz * _iK;       \
        smallest_eigvec(_sxx * _iK - _mx * _mx, _sxy * _iK - _mx * _my, \
                        _sxz * _iK - _mx * _mz, _syy * _iK - _my * _my, \
                        _syz * _iK - _my * _mz, _szz * _iK - _mz * _mz, \
                        vx, vy, vz);                                   \
    } while (0)

__global__ void zero_out_kernel(float* __restrict__ out) {
    if (threadIdx.x == 0) out[0] = 0.0f;
}

// One block = 128 points of one batch, BOTH clouds. 8 waves; lane l owns
// points (base+l, base+l+64); wave w scans segment w (wave-uniform broadcast
// LDS reads, Q=2 amortization). Loss computed in-block, one atomicAdd.
__global__ __launch_bounds__(TPB, 2) void knn_normal_loss(
    const float* __restrict__ pred, const float* __restrict__ gt,
    float* __restrict__ out) {
    __shared__ float4 pts[HALFPTS + 8];   // +8: prefetch over-read pad (never consumed)

    const int b = blockIdx.y;
    const float* __restrict__ baseP = pred + b * 3 * NPTS;
    const float* __restrict__ baseG = gt + b * 3 * NPTS;
    const int tid = threadIdx.x;
    const int lane = tid & 63;
    const int w = tid >> 6;           // wave id = segment id
    const int s0 = w * SEGC;          // wave-uniform segment offset
    float* keybuf = (float*)pts;

    const int pt0 = blockIdx.x * QPB + lane;
    const int pt1 = pt0 + 64;

    float kP0[KNN], kP1[KNN];         // pred top-10 (final in wave 0)
    float kG0[KNN], kG1[KNN];         // gt   top-10 (final in wave 0)

    SCAN_CLOUD(baseP, kP0, kP1);
    SCAN_CLOUD(baseG, kG0, kG1);

    if (w == 0) {
        float acc;
        {
            float pvx, pvy, pvz, gvx, gvy, gvz;
            COMPUTE_NORMAL(kP0, baseP, pvx, pvy, pvz);
            COMPUTE_NORMAL(kG0, baseG, gvx, gvy, gvz);
            float dot = pvx * gvx + pvy * gvy + pvz * gvz;
            float npn = sqrtf(pvx * pvx + pvy * pvy + pvz * pvz);
            float ngn = sqrtf(gvx * gvx + gvy * gvy + gvz * gvz);
            acc = 1.0f - fabsf(dot / fmaxf(npn * ngn, 1e-8f));
        }
        {
            float pvx, pvy, pvz, gvx, gvy, gvz;
            COMPUTE_NORMAL(kP1, baseP, pvx, pvy, pvz);
            COMPUTE_NORMAL(kG1, baseG, gvx, gvy, gvz);
            float dot = pvx * gvx + pvy * gvy + pvz * gvz;
            float npn = sqrtf(pvx * pvx + pvy * pvy + pvz * pvz);
            float ngn = sqrtf(gvx * gvx + gvy * gvy + gvz * gvz);
            acc += 1.0f - fabsf(dot / fmaxf(npn * ngn, 1e-8f));
        }
        // wave reduction, then one atomic per block
        for (int off = 32; off > 0; off >>= 1) acc += __shfl_down(acc, off);
        if (lane == 0) atomicAdd(out, acc * (1.0f / (float)BN));
    }
}

extern "C" void kernel_launch(void* const* d_in, const int* in_sizes, int n_in,
                              void* d_out, int out_size, void* d_ws, size_t ws_size,
                              hipStream_t stream) {
    const float* pred = (const float*)d_in[0];
    const float* gt = (const float*)d_in[1];
    float* out = (float*)d_out;

    zero_out_kernel<<<1, 64, 0, stream>>>(out);
    dim3 grid(GRIDX, BATCH);          // 32 x 8 = 256 blocks (1 per CU)
    knn_normal_loss<<<grid, TPB, 0, stream>>>(pred, gt, out);
}